// Round 5
// baseline (1180.893 us; speedup 1.0000x reference)
//
#include <hip/hip_runtime.h>
#include <hip/hip_bf16.h>
#include <stdint.h>

#define VOCAB 10000
#define HID   256
#define BATCH 32
#define STEPS 256

typedef __attribute__((ext_vector_type(8))) short short8;
typedef __attribute__((ext_vector_type(4))) float floatx4;

__device__ __forceinline__ float bf2f(unsigned short u) {
    union { unsigned int ui; float f; } v;
    v.ui = ((unsigned int)u) << 16;
    return v.f;
}

__device__ __forceinline__ unsigned short f2bf(float f) {
    union { float f; unsigned int ui; } v;
    v.f = f;
    unsigned int u = v.ui;
    unsigned int r = (u + 0x7FFFu + ((u >> 16) & 1u)) >> 16;  // RNE
    return (unsigned short)r;
}

// packed bf16x2 dot product: acc += lo(w)*lo(h) + hi(w)*hi(h)
#if __has_builtin(__builtin_amdgcn_fdot2_f32_bf16)
typedef __bf16 bf16x2 __attribute__((ext_vector_type(2)));
__device__ __forceinline__ float dot2(unsigned int w, unsigned int h, float acc) {
    union { unsigned int u; bf16x2 v; } a, b;
    a.u = w; b.u = h;
    return __builtin_amdgcn_fdot2_f32_bf16(a.v, b.v, acc, false);
}
#else
__device__ __forceinline__ float dot2(unsigned int w, unsigned int h, float acc) {
    union { unsigned int u; float f; } w0, w1, h0, h1;
    w0.u = w << 16; w1.u = w & 0xFFFF0000u;
    h0.u = h << 16; h1.u = h & 0xFFFF0000u;
    acc = fmaf(w0.f, h0.f, acc);
    acc = fmaf(w1.f, h1.f, acc);
    return acc;
}
#endif

__device__ __forceinline__ float sigmoidf_(float x) {
    return __builtin_amdgcn_rcpf(1.0f + __expf(-x));
}
__device__ __forceinline__ float tanhf_(float x) {
    // 1 - 2/(exp(2x)+1); correct limits at +-inf with v_exp
    float e = __expf(2.0f * x);
    return 1.0f - 2.0f * __builtin_amdgcn_rcpf(e + 1.0f);
}

// ---------------------------------------------------------------------------
// prep_w: Whz/Whr/Whh f32[256][256] -> Wsw[g][p4(32)][j(256)][m(8)] bf16
// grid (3, 32), 256 thr. Coalesced f32 row reads; contiguous 16B short8 writes.
// ---------------------------------------------------------------------------
__global__ void prep_w(const float* __restrict__ Wz, const float* __restrict__ Wr,
                       const float* __restrict__ Wh, unsigned short* __restrict__ out) {
    int g = blockIdx.x, p4 = blockIdx.y, j = threadIdx.x;
    const float* W = (g == 0) ? Wz : (g == 1) ? Wr : Wh;
    union { unsigned short us[8]; short8 v; } pk;
    #pragma unroll
    for (int m = 0; m < 8; ++m)
        pk.us[m] = f2bf(W[(p4 * 8 + m) * HID + j]);
    *(short8*)(out + (((size_t)g * 32 + p4) * HID + j) * 8) = pk.v;
}

// ---------------------------------------------------------------------------
// prep_b: Whq f32[256][10000] -> B-fragment buffer for mfma_16x16x32_bf16
//   bfr[nt(625)][kc(8)][lane(64)][jj(8)] = Whq[kc*32 + (lane>>4)*8 + jj][nt*16 + (lane&15)]
// grid (40, 8). LDS transpose: coalesced loads -> contiguous 16B short8 writes.
// ---------------------------------------------------------------------------
__global__ void prep_b(const float* __restrict__ Whq, unsigned short* __restrict__ bfr) {
    __shared__ float lds[32][257];   // +1 pad breaks bank aliasing on the gather
    const int nb = blockIdx.x;       // 0..39  (256 cols each)
    const int kc = blockIdx.y;       // 0..7   (32 k-rows each)
    const int tid = threadIdx.x;
    const int n0 = nb * 256;

    #pragma unroll 4
    for (int kk = 0; kk < 32; ++kk) {
        int n = n0 + tid;
        float v = (n < VOCAB) ? Whq[(size_t)(kc * 32 + kk) * VOCAB + n] : 0.0f;
        lds[kk][tid] = v;
    }
    __syncthreads();

    const int lane = tid & 63;
    const int wq   = tid >> 6;       // 0..3
    const int quad = lane >> 4, l15 = lane & 15;
    #pragma unroll
    for (int ntp = 0; ntp < 4; ++ntp) {
        int nt_local = ntp * 4 + wq;
        int nt = nb * 16 + nt_local;
        if (nt >= 625) continue;
        union { unsigned short us[8]; short8 v; } pk;
        #pragma unroll
        for (int jj = 0; jj < 8; ++jj)
            pk.us[jj] = f2bf(lds[quad * 8 + jj][nt_local * 16 + l15]);
        *(short8*)(bfr + (((size_t)nt * 8 + kc) * 64 + lane) * 8) = pk.v;
    }
}

// ---------------------------------------------------------------------------
// prep_a: hist[8192][256] bf16 -> A-fragment buffer Afr[MT(512)][kc(8)][lane(64)][8]
//   Afr[MT][kc][lane][jj] = hist[MT*16 + (lane&15)][kc*32 + (lane>>4)*8 + jj]
// ---------------------------------------------------------------------------
__global__ __launch_bounds__(256) void prep_a(const unsigned short* __restrict__ hist,
                                              unsigned short* __restrict__ afr) {
    __shared__ __align__(16) unsigned short tile[16 * 256];
    const int MT = blockIdx.x;       // 0..511
    const int tid = threadIdx.x;

    const uint4* src = (const uint4*)(hist + (size_t)MT * 16 * 256);
    uint4* dst = (uint4*)tile;
    dst[tid]       = src[tid];
    dst[tid + 256] = src[tid + 256];
    __syncthreads();

    #pragma unroll
    for (int i = 0; i < 2; ++i) {
        int s = tid * 2 + i;         // 0..511 = kc*64 + lane
        int kc = s >> 6, lane = s & 63;
        int quad = lane >> 4, l15 = lane & 15;
        const unsigned short* p = tile + l15 * 256 + kc * 32 + quad * 8;
        *(short8*)(afr + (((size_t)MT * 8 + kc) * 64 + lane) * 8) = *(const short8*)p;
    }
}

// ---------------------------------------------------------------------------
// gru_rec: 32 blocks (one batch row) x 256 threads (4 waves). MERGED groups:
// every thread j owns column j of ALL THREE gates.
//   - One hv read feeds 8 dot2 (z and r share the hbuf stream): LDS broadcast
//     wave-ops drop from 384 to 256 per step (the measured bottleneck).
//   - 2 barriers/step (was 3); no part[] exchange; no B-side h copy.
//   - All 3 weight columns hoisted to VGPRs: 96 x uint4 = 384 VGPRs.
//     __launch_bounds__(256,1) allows ~450 VGPR at 1 wave/SIMD (no spill).
//   - xrow[nxt] published at the END of the step (before B2): global prefetch
//     gets a full step (~900 cyc) to land instead of half a phase.
// ---------------------------------------------------------------------------
__global__ __launch_bounds__(256, 1) void gru_rec(
    const int* __restrict__ X, const float* __restrict__ H0,
    const float* __restrict__ Wxz, const float* __restrict__ Wxr,
    const float* __restrict__ Wxh,
    const float* __restrict__ bz, const float* __restrict__ br,
    const float* __restrict__ bh,
    const unsigned short* __restrict__ Wsw,
    unsigned short* __restrict__ hist,   // [STEPS*BATCH][HID] bf16
    float* __restrict__ h_final)         // [BATCH][HID] f32
{
    const int b = blockIdx.x;
    const int j = threadIdx.x;           // 0..255

    __shared__ __align__(16) unsigned short hbuf[HID];
    __shared__ __align__(16) unsigned short rhbuf[HID];
    __shared__ float xrow[2][3][HID];
    __shared__ int Xl[STEPS];

    const uint4* wz = (const uint4*)Wsw + j;                      // g=0
    const uint4* wr = (const uint4*)Wsw + (size_t)1 * 32 * HID + j;
    const uint4* wh = (const uint4*)Wsw + (size_t)2 * 32 * HID + j;

    float h_my = H0[b * HID + j];
    const float bzj = bz[j], brj = br[j], bhj = bh[j];

    // ---- hoist all loop-invariant weights into registers (static idx only) ----
    uint4 wzreg[32], wrreg[32], whreg[32];
    #pragma unroll
    for (int i = 0; i < 32; ++i) wzreg[i] = wz[i * HID];
    #pragma unroll
    for (int i = 0; i < 32; ++i) wrreg[i] = wr[i * HID];
    #pragma unroll
    for (int i = 0; i < 32; ++i) whreg[i] = wh[i * HID];

    hbuf[j] = f2bf(h_my);
    Xl[j] = X[b * STEPS + j];
    __syncthreads();

    {   // initial x-row gather for t=0
        int x0 = Xl[0];
        xrow[0][0][j] = Wxz[(size_t)x0 * HID + j];
        xrow[0][1][j] = Wxr[(size_t)x0 * HID + j];
        xrow[0][2][j] = Wxh[(size_t)x0 * HID + j];
    }
    __syncthreads();

    for (int t = 0; t < STEPS; ++t) {
        const int cur = t & 1, nxt = cur ^ 1;

        // prefetch next step's x-projection rows (published before B2)
        const int xn = Xl[(t + 1) & (STEPS - 1)];
        float p0 = Wxz[(size_t)xn * HID + j];
        float p1 = Wxr[(size_t)xn * HID + j];
        float p2 = Wxh[(size_t)xn * HID + j];

        // z AND r dots: one hv read feeds 8 dot2
        float z0 = 0.f, z1 = 0.f, z2 = 0.f, z3 = 0.f;
        float r0 = 0.f, r1 = 0.f, r2 = 0.f, r3 = 0.f;
        {
            const uint4* hp = (const uint4*)hbuf;
            #pragma unroll
            for (int i = 0; i < 32; ++i) {
                uint4 hv = hp[i];
                z0 = dot2(wzreg[i].x, hv.x, z0);
                z1 = dot2(wzreg[i].y, hv.y, z1);
                z2 = dot2(wzreg[i].z, hv.z, z2);
                z3 = dot2(wzreg[i].w, hv.w, z3);
                r0 = dot2(wrreg[i].x, hv.x, r0);
                r1 = dot2(wrreg[i].y, hv.y, r1);
                r2 = dot2(wrreg[i].z, hv.z, r2);
                r3 = dot2(wrreg[i].w, hv.w, r3);
            }
        }
        float z = sigmoidf_(((z0 + z1) + (z2 + z3)) + xrow[cur][0][j] + bzj);
        float r = sigmoidf_(((r0 + r1) + (r2 + r3)) + xrow[cur][1][j] + brj);
        rhbuf[j] = f2bf(r * h_my);
        __syncthreads();  // B1: rhbuf published (hbuf reads all done)

        // h-gate: full-K dot over rhbuf
        float a0 = 0.f, a1 = 0.f, a2 = 0.f, a3 = 0.f;
        {
            const uint4* rp = (const uint4*)rhbuf;
            #pragma unroll
            for (int i = 0; i < 32; ++i) {
                uint4 hv = rp[i];
                a0 = dot2(whreg[i].x, hv.x, a0);
                a1 = dot2(whreg[i].y, hv.y, a1);
                a2 = dot2(whreg[i].z, hv.z, a2);
                a3 = dot2(whreg[i].w, hv.w, a3);
            }
        }
        float hpre = ((a0 + a1) + (a2 + a3)) + xrow[cur][2][j] + bhj;
        float ht = tanhf_(hpre);
        float hn = z * h_my + (1.0f - z) * ht;
        h_my = hn;
        unsigned short hb = f2bf(hn);
        hist[((size_t)t * BATCH + b) * HID + j] = hb;

        // late publish: next x-rows + new h
        xrow[nxt][0][j] = p0;
        xrow[nxt][1][j] = p1;
        xrow[nxt][2][j] = p2;
        hbuf[j] = hb;
        __syncthreads();  // B2: hbuf + xrow[nxt] visible; rhbuf free for reuse
    }

    h_final[b * HID + j] = h_my;
}

// ---------------------------------------------------------------------------
// proj: C[8192][10000] = A[8192][256](bf16) @ B[256][10000](bf16) + bq, f32 out
// UNCHANGED (needs its own counters; surfaces to top-5 this round).
// ---------------------------------------------------------------------------
__global__ __launch_bounds__(256, 2) void proj(
    const unsigned short* __restrict__ Afr,  // [512][8][64][8]
    const unsigned short* __restrict__ Bfr,  // [625][8][64][8]
    const float* __restrict__ bq,
    float* __restrict__ C)
{
    const int tid  = threadIdx.x;
    const int wave = tid >> 6;
    const int lane = tid & 63;
    const int l15  = lane & 15;
    const int quad = lane >> 4;

    // XCD-aware decode: blocks on one XCD share a 5-nb B-slice, sweep mb.
    const int orig = blockIdx.x;        // 0..2559
    const int xcd  = orig & 7;
    const int idx  = orig >> 3;         // 0..319
    const int mb   = idx / 5;           // 0..63
    const int nb   = xcd * 5 + (idx % 5);  // 0..39

    const int m0 = mb * 128;
    const int nt0 = nb * 16 + wave * 4;

    floatx4 acc[8][4];
    #pragma unroll
    for (int i = 0; i < 8; ++i)
        #pragma unroll
        for (int q = 0; q < 4; ++q)
            acc[i][q] = (floatx4)0.0f;

    int ntc[4];
    #pragma unroll
    for (int q = 0; q < 4; ++q) {
        int nt = nt0 + q;
        ntc[q] = (nt < 625) ? nt : 624;
    }

    for (int kc = 0; kc < 8; ++kc) {
        short8 a[8];
        #pragma unroll
        for (int mt = 0; mt < 8; ++mt) {
            const unsigned short* ap =
                Afr + (((size_t)(mb * 8 + mt) * 8 + kc) * 64 + lane) * 8;
            a[mt] = *(const short8*)ap;
        }
        short8 bfrg[4];
        #pragma unroll
        for (int q = 0; q < 4; ++q) {
            const unsigned short* bp =
                Bfr + ((((size_t)ntc[q] * 8 + kc) * 64) + lane) * 8;
            bfrg[q] = *(const short8*)bp;
        }
        // operands SWAPPED: lane holds C[m0+mt*16+l15][nt*16+quad*4 + r]
        #pragma unroll
        for (int mt = 0; mt < 8; ++mt)
            #pragma unroll
            for (int q = 0; q < 4; ++q)
                acc[mt][q] = __builtin_amdgcn_mfma_f32_16x16x32_bf16(
                    bfrg[q], a[mt], acc[mt][q], 0, 0, 0);
    }

    // epilogue: bias + non-temporal float4 stores (4 consecutive cols per lane)
    floatx4 bq4[4];
    #pragma unroll
    for (int q = 0; q < 4; ++q) {
        int nt = nt0 + q;
        bq4[q] = (nt < 625) ? *(const floatx4*)(bq + nt * 16 + quad * 4)
                            : (floatx4)0.0f;
    }
    #pragma unroll
    for (int mt = 0; mt < 8; ++mt) {
        const size_t rowoff = (size_t)(m0 + mt * 16 + l15) * VOCAB;
        #pragma unroll
        for (int q = 0; q < 4; ++q) {
            int nt = nt0 + q;
            if (nt >= 625) continue;
            floatx4 v = acc[mt][q] + bq4[q];
            __builtin_nontemporal_store(v, (floatx4*)(C + rowoff + nt * 16 + quad * 4));
        }
    }
}

// ---------------------------------------------------------------------------
extern "C" void kernel_launch(void* const* d_in, const int* in_sizes, int n_in,
                              void* d_out, int out_size, void* d_ws, size_t ws_size,
                              hipStream_t stream) {
    const int*   X   = (const int*)  d_in[0];
    const float* H0  = (const float*)d_in[1];
    const float* Wxz = (const float*)d_in[2];
    const float* Whz = (const float*)d_in[3];
    const float* bz  = (const float*)d_in[4];
    const float* Wxr = (const float*)d_in[5];
    const float* Whr = (const float*)d_in[6];
    const float* br  = (const float*)d_in[7];
    const float* Wxh = (const float*)d_in[8];
    const float* Whh = (const float*)d_in[9];
    const float* bh  = (const float*)d_in[10];
    const float* Whq = (const float*)d_in[11];
    const float* bq  = (const float*)d_in[12];

    float* out     = (float*)d_out;
    float* h_final = out + (size_t)STEPS * BATCH * VOCAB;

    // ws layout (ushorts): Wsw[196608] | Bfr[2560000] | hist[2097152] | Afr[2097152]
    unsigned short* wsw  = (unsigned short*)d_ws;
    unsigned short* bfr  = wsw + 196608;
    unsigned short* hist = bfr + 2560000;
    unsigned short* afr  = hist + 2097152;

    prep_w<<<dim3(3, 32), 256, 0, stream>>>(Whz, Whr, Whh, wsw);
    prep_b<<<dim3(40, 8), 256, 0, stream>>>(Whq, bfr);
    gru_rec<<<BATCH, 256, 0, stream>>>(X, H0, Wxz, Wxr, Wxh, bz, br, bh,
                                       wsw, hist, h_final);
    prep_a<<<512, 256, 0, stream>>>(hist, afr);
    proj<<<2560, 256, 0, stream>>>(afr, bfr, bq, out);
}

// Round 6
// 822.016 us; speedup vs baseline: 1.4366x; 1.4366x over previous
//
#include <hip/hip_runtime.h>
#include <hip/hip_bf16.h>
#include <stdint.h>

#define VOCAB 10000
#define HID   256
#define BATCH 32
#define STEPS 256

typedef __attribute__((ext_vector_type(8))) short short8;
typedef __attribute__((ext_vector_type(4))) float floatx4;

// keep a loaded value alive in a VGPR: asm becomes the producer, so the
// compiler cannot rematerialize (re-issue) the originating load in-loop.
#define PIN4(v) asm volatile("" : "+v"((v).x), "+v"((v).y), "+v"((v).z), "+v"((v).w))

__device__ __forceinline__ float bf2f(unsigned short u) {
    union { unsigned int ui; float f; } v;
    v.ui = ((unsigned int)u) << 16;
    return v.f;
}

__device__ __forceinline__ unsigned short f2bf(float f) {
    union { float f; unsigned int ui; } v;
    v.f = f;
    unsigned int u = v.ui;
    unsigned int r = (u + 0x7FFFu + ((u >> 16) & 1u)) >> 16;  // RNE
    return (unsigned short)r;
}

// packed bf16x2 dot product: acc += lo(w)*lo(h) + hi(w)*hi(h)
#if __has_builtin(__builtin_amdgcn_fdot2_f32_bf16)
typedef __bf16 bf16x2 __attribute__((ext_vector_type(2)));
__device__ __forceinline__ float dot2(unsigned int w, unsigned int h, float acc) {
    union { unsigned int u; bf16x2 v; } a, b;
    a.u = w; b.u = h;
    return __builtin_amdgcn_fdot2_f32_bf16(a.v, b.v, acc, false);
}
#else
__device__ __forceinline__ float dot2(unsigned int w, unsigned int h, float acc) {
    union { unsigned int u; float f; } w0, w1, h0, h1;
    w0.u = w << 16; w1.u = w & 0xFFFF0000u;
    h0.u = h << 16; h1.u = h & 0xFFFF0000u;
    acc = fmaf(w0.f, h0.f, acc);
    acc = fmaf(w1.f, h1.f, acc);
    return acc;
}
#endif

__device__ __forceinline__ float sigmoidf_(float x) {
    return __builtin_amdgcn_rcpf(1.0f + __expf(-x));
}
__device__ __forceinline__ float tanhf_(float x) {
    // 1 - 2/(exp(2x)+1); correct limits at +-inf with v_exp
    float e = __expf(2.0f * x);
    return 1.0f - 2.0f * __builtin_amdgcn_rcpf(e + 1.0f);
}

// ---------------------------------------------------------------------------
// prep_w: Whz/Whr/Whh f32[256][256] -> Wsw[g][p4(32)][j(256)][m(8)] bf16
// grid (3, 32), 256 thr. Coalesced f32 row reads; contiguous 16B short8 writes.
// ---------------------------------------------------------------------------
__global__ void prep_w(const float* __restrict__ Wz, const float* __restrict__ Wr,
                       const float* __restrict__ Wh, unsigned short* __restrict__ out) {
    int g = blockIdx.x, p4 = blockIdx.y, j = threadIdx.x;
    const float* W = (g == 0) ? Wz : (g == 1) ? Wr : Wh;
    union { unsigned short us[8]; short8 v; } pk;
    #pragma unroll
    for (int m = 0; m < 8; ++m)
        pk.us[m] = f2bf(W[(p4 * 8 + m) * HID + j]);
    *(short8*)(out + (((size_t)g * 32 + p4) * HID + j) * 8) = pk.v;
}

// ---------------------------------------------------------------------------
// prep_b: Whq f32[256][10000] -> B-fragment buffer for mfma_16x16x32_bf16
//   bfr[nt(625)][kc(8)][lane(64)][jj(8)] = Whq[kc*32 + (lane>>4)*8 + jj][nt*16 + (lane&15)]
// grid (40, 8). LDS transpose: coalesced loads -> contiguous 16B short8 writes.
// ---------------------------------------------------------------------------
__global__ void prep_b(const float* __restrict__ Whq, unsigned short* __restrict__ bfr) {
    __shared__ float lds[32][257];   // +1 pad breaks bank aliasing on the gather
    const int nb = blockIdx.x;       // 0..39  (256 cols each)
    const int kc = blockIdx.y;       // 0..7   (32 k-rows each)
    const int tid = threadIdx.x;
    const int n0 = nb * 256;

    #pragma unroll 4
    for (int kk = 0; kk < 32; ++kk) {
        int n = n0 + tid;
        float v = (n < VOCAB) ? Whq[(size_t)(kc * 32 + kk) * VOCAB + n] : 0.0f;
        lds[kk][tid] = v;
    }
    __syncthreads();

    const int lane = tid & 63;
    const int wq   = tid >> 6;       // 0..3
    const int quad = lane >> 4, l15 = lane & 15;
    #pragma unroll
    for (int ntp = 0; ntp < 4; ++ntp) {
        int nt_local = ntp * 4 + wq;
        int nt = nb * 16 + nt_local;
        if (nt >= 625) continue;
        union { unsigned short us[8]; short8 v; } pk;
        #pragma unroll
        for (int jj = 0; jj < 8; ++jj)
            pk.us[jj] = f2bf(lds[quad * 8 + jj][nt_local * 16 + l15]);
        *(short8*)(bfr + (((size_t)nt * 8 + kc) * 64 + lane) * 8) = pk.v;
    }
}

// ---------------------------------------------------------------------------
// prep_a: hist[8192][256] bf16 -> A-fragment buffer Afr[MT(512)][kc(8)][lane(64)][8]
//   Afr[MT][kc][lane][jj] = hist[MT*16 + (lane&15)][kc*32 + (lane>>4)*8 + jj]
// ---------------------------------------------------------------------------
__global__ __launch_bounds__(256) void prep_a(const unsigned short* __restrict__ hist,
                                              unsigned short* __restrict__ afr) {
    __shared__ __align__(16) unsigned short tile[16 * 256];
    const int MT = blockIdx.x;       // 0..511
    const int tid = threadIdx.x;

    const uint4* src = (const uint4*)(hist + (size_t)MT * 16 * 256);
    uint4* dst = (uint4*)tile;
    dst[tid]       = src[tid];
    dst[tid + 256] = src[tid + 256];
    __syncthreads();

    #pragma unroll
    for (int i = 0; i < 2; ++i) {
        int s = tid * 2 + i;         // 0..511 = kc*64 + lane
        int kc = s >> 6, lane = s & 63;
        int quad = lane >> 4, l15 = lane & 15;
        const unsigned short* p = tile + l15 * 256 + kc * 32 + quad * 8;
        *(short8*)(afr + (((size_t)MT * 8 + kc) * 64 + lane) * 8) = *(const short8*)p;
    }
}

// ---------------------------------------------------------------------------
// gru_rec: REVERTED to the round-3 split structure (known-good 373 us) + PIN.
// 32 blocks x 512 threads (8 waves, 2/SIMD -> 256-reg/thread budget).
//   Group A (tid<256, col j): z-gate full-K dot, h-gate K-low half,
//                             activations/blend, owns the f32 h chain.
//   Group B (col j): r-gate full-K dot, rh, h-gate K-high half.
// Weight residency: 48 x uint4 = 192 regs/thread, PINNED via empty asm so the
// compiler cannot rematerialize the loads in-loop (round-3 kept only ~half
// resident -> re-streamed ~200KB/step from L2 = the 3500cyc/step bottleneck).
// ---------------------------------------------------------------------------
__global__ __launch_bounds__(512, 1) void gru_rec(
    const int* __restrict__ X, const float* __restrict__ H0,
    const float* __restrict__ Wxz, const float* __restrict__ Wxr,
    const float* __restrict__ Wxh,
    const float* __restrict__ bz, const float* __restrict__ br,
    const float* __restrict__ bh,
    const unsigned short* __restrict__ Wsw,
    unsigned short* __restrict__ hist,   // [STEPS*BATCH][HID] bf16
    float* __restrict__ h_final)         // [BATCH][HID] f32
{
    const int b = blockIdx.x;
    const int tid = threadIdx.x;
    const bool isA = tid < HID;
    const int j = isA ? tid : tid - HID;

    __shared__ __align__(16) unsigned short hbuf[HID];
    __shared__ __align__(16) unsigned short rhbuf[HID];
    __shared__ float part[HID];
    __shared__ float xrow[2][3][HID];
    __shared__ int Xl[STEPS];

    const uint4* wA = (const uint4*)Wsw + (size_t)(isA ? 0 : 1) * 32 * HID + j; // z or r
    const uint4* wH = (const uint4*)Wsw + (size_t)2 * 32 * HID + j;             // h

    float h_my = H0[b * HID + j];
    float bias = isA ? bz[j] : br[j];
    float bhj  = isA ? bh[j] : 0.0f;

    // ---- hoist loop-invariant weights into registers, then PIN them ----
    uint4 wreg[32];          // full-K column of W_hz (A) / W_hr (B): 128 regs
    #pragma unroll
    for (int i = 0; i < 32; ++i) wreg[i] = wA[i * HID];

    const int i0 = isA ? 0 : 16;
    uint4 whreg[16];         // K-half column of W_hh: 64 regs
    #pragma unroll
    for (int i = 0; i < 16; ++i) whreg[i] = wH[(i0 + i) * HID];

    #pragma unroll
    for (int i = 0; i < 32; ++i) PIN4(wreg[i]);
    #pragma unroll
    for (int i = 0; i < 16; ++i) PIN4(whreg[i]);

    if (isA) { hbuf[j] = f2bf(h_my); Xl[j] = X[b * STEPS + j]; }
    __syncthreads();

    {   // initial x-row gather for t=0
        int x0 = Xl[0];
        if (isA) {
            xrow[0][0][j] = Wxz[(size_t)x0 * HID + j];
            xrow[0][2][j] = Wxh[(size_t)x0 * HID + j];
        } else {
            xrow[0][1][j] = Wxr[(size_t)x0 * HID + j];
        }
    }
    __syncthreads();

    float z = 0.0f;

    for (int t = 0; t < STEPS; ++t) {
        const int cur = t & 1, nxt = cur ^ 1;

        // prefetch next step's x-projection rows (wraps harmlessly at t=255)
        const int xn = Xl[(t + 1) & (STEPS - 1)];
        float p0 = 0.f, p1 = 0.f;
        if (isA) {
            p0 = Wxz[(size_t)xn * HID + j];
            p1 = Wxh[(size_t)xn * HID + j];
        } else {
            p0 = Wxr[(size_t)xn * HID + j];
        }

        // z-gate (A) / r-gate (B): full-K dot over h pairs, weights from VGPRs
        float acc;
        {
            const uint4* hp = (const uint4*)hbuf;
            float a0 = 0.f, a1 = 0.f, a2 = 0.f, a3 = 0.f;
            #pragma unroll
            for (int i = 0; i < 32; ++i) {
                uint4 hv = hp[i];
                a0 = dot2(wreg[i].x, hv.x, a0);
                a1 = dot2(wreg[i].y, hv.y, a1);
                a2 = dot2(wreg[i].z, hv.z, a2);
                a3 = dot2(wreg[i].w, hv.w, a3);
            }
            acc = (a0 + a1) + (a2 + a3);
        }

        if (isA) {
            z = sigmoidf_(acc + xrow[cur][0][j] + bias);
            xrow[nxt][0][j] = p0;
            xrow[nxt][2][j] = p1;
        } else {
            float r = sigmoidf_(acc + xrow[cur][1][j] + bias);
            rhbuf[j] = f2bf(r * h_my);
            xrow[nxt][1][j] = p0;
        }
        __syncthreads();  // B1: rhbuf + xrow[nxt] published

        // h-gate: K split between groups (A: pairs 0..63, B: 64..127)
        float acch;
        {
            const uint4* rp = (const uint4*)rhbuf;
            float a0 = 0.f, a1 = 0.f, a2 = 0.f, a3 = 0.f;
            #pragma unroll
            for (int i = 0; i < 16; ++i) {
                uint4 hv = rp[i0 + i];
                a0 = dot2(whreg[i].x, hv.x, a0);
                a1 = dot2(whreg[i].y, hv.y, a1);
                a2 = dot2(whreg[i].z, hv.z, a2);
                a3 = dot2(whreg[i].w, hv.w, a3);
            }
            acch = (a0 + a1) + (a2 + a3);
        }
        if (!isA) part[j] = acch;
        __syncthreads();  // B2: h-gate partials published

        if (isA) {
            float hpre = acch + part[j] + xrow[cur][2][j] + bhj;
            float ht = tanhf_(hpre);
            float hn = z * h_my + (1.0f - z) * ht;
            h_my = hn;
            unsigned short hb = f2bf(hn);
            hbuf[j] = hb;
            hist[((size_t)t * BATCH + b) * HID + j] = hb;
        }
        __syncthreads();  // B3: hbuf published

        if (!isA) h_my = bf2f(hbuf[j]);  // B's h copy (bf16-rounded, used only for rh)
    }

    if (isA) h_final[b * HID + j] = h_my;
}

// ---------------------------------------------------------------------------
// proj: C[8192][10000] = A[8192][256](bf16) @ B[256][10000](bf16) + bq, f32 out
// UNCHANGED (surfaces to top-5 once gru drops; need its counters).
// ---------------------------------------------------------------------------
__global__ __launch_bounds__(256, 2) void proj(
    const unsigned short* __restrict__ Afr,  // [512][8][64][8]
    const unsigned short* __restrict__ Bfr,  // [625][8][64][8]
    const float* __restrict__ bq,
    float* __restrict__ C)
{
    const int tid  = threadIdx.x;
    const int wave = tid >> 6;
    const int lane = tid & 63;
    const int l15  = lane & 15;
    const int quad = lane >> 4;

    // XCD-aware decode: blocks on one XCD share a 5-nb B-slice, sweep mb.
    const int orig = blockIdx.x;        // 0..2559
    const int xcd  = orig & 7;
    const int idx  = orig >> 3;         // 0..319
    const int mb   = idx / 5;           // 0..63
    const int nb   = xcd * 5 + (idx % 5);  // 0..39

    const int m0 = mb * 128;
    const int nt0 = nb * 16 + wave * 4;

    floatx4 acc[8][4];
    #pragma unroll
    for (int i = 0; i < 8; ++i)
        #pragma unroll
        for (int q = 0; q < 4; ++q)
            acc[i][q] = (floatx4)0.0f;

    int ntc[4];
    #pragma unroll
    for (int q = 0; q < 4; ++q) {
        int nt = nt0 + q;
        ntc[q] = (nt < 625) ? nt : 624;
    }

    for (int kc = 0; kc < 8; ++kc) {
        short8 a[8];
        #pragma unroll
        for (int mt = 0; mt < 8; ++mt) {
            const unsigned short* ap =
                Afr + (((size_t)(mb * 8 + mt) * 8 + kc) * 64 + lane) * 8;
            a[mt] = *(const short8*)ap;
        }
        short8 bfrg[4];
        #pragma unroll
        for (int q = 0; q < 4; ++q) {
            const unsigned short* bp =
                Bfr + ((((size_t)ntc[q] * 8 + kc) * 64) + lane) * 8;
            bfrg[q] = *(const short8*)bp;
        }
        // operands SWAPPED: lane holds C[m0+mt*16+l15][nt*16+quad*4 + r]
        #pragma unroll
        for (int mt = 0; mt < 8; ++mt)
            #pragma unroll
            for (int q = 0; q < 4; ++q)
                acc[mt][q] = __builtin_amdgcn_mfma_f32_16x16x32_bf16(
                    bfrg[q], a[mt], acc[mt][q], 0, 0, 0);
    }

    // epilogue: bias + non-temporal float4 stores (4 consecutive cols per lane)
    floatx4 bq4[4];
    #pragma unroll
    for (int q = 0; q < 4; ++q) {
        int nt = nt0 + q;
        bq4[q] = (nt < 625) ? *(const floatx4*)(bq + nt * 16 + quad * 4)
                            : (floatx4)0.0f;
    }
    #pragma unroll
    for (int mt = 0; mt < 8; ++mt) {
        const size_t rowoff = (size_t)(m0 + mt * 16 + l15) * VOCAB;
        #pragma unroll
        for (int q = 0; q < 4; ++q) {
            int nt = nt0 + q;
            if (nt >= 625) continue;
            floatx4 v = acc[mt][q] + bq4[q];
            __builtin_nontemporal_store(v, (floatx4*)(C + rowoff + nt * 16 + quad * 4));
        }
    }
}

// ---------------------------------------------------------------------------
extern "C" void kernel_launch(void* const* d_in, const int* in_sizes, int n_in,
                              void* d_out, int out_size, void* d_ws, size_t ws_size,
                              hipStream_t stream) {
    const int*   X   = (const int*)  d_in[0];
    const float* H0  = (const float*)d_in[1];
    const float* Wxz = (const float*)d_in[2];
    const float* Whz = (const float*)d_in[3];
    const float* bz  = (const float*)d_in[4];
    const float* Wxr = (const float*)d_in[5];
    const float* Whr = (const float*)d_in[6];
    const float* br  = (const float*)d_in[7];
    const float* Wxh = (const float*)d_in[8];
    const float* Whh = (const float*)d_in[9];
    const float* bh  = (const float*)d_in[10];
    const float* Whq = (const float*)d_in[11];
    const float* bq  = (const float*)d_in[12];

    float* out     = (float*)d_out;
    float* h_final = out + (size_t)STEPS * BATCH * VOCAB;

    // ws layout (ushorts): Wsw[196608] | Bfr[2560000] | hist[2097152] | Afr[2097152]
    unsigned short* wsw  = (unsigned short*)d_ws;
    unsigned short* bfr  = wsw + 196608;
    unsigned short* hist = bfr + 2560000;
    unsigned short* afr  = hist + 2097152;

    prep_w<<<dim3(3, 32), 256, 0, stream>>>(Whz, Whr, Whh, wsw);
    prep_b<<<dim3(40, 8), 256, 0, stream>>>(Whq, bfr);
    gru_rec<<<BATCH, 512, 0, stream>>>(X, H0, Wxz, Wxr, Wxh, bz, br, bh,
                                       wsw, hist, h_final);
    prep_a<<<512, 256, 0, stream>>>(hist, afr);
    proj<<<2560, 256, 0, stream>>>(afr, bfr, bq, out);
}

// Round 7
// 815.634 us; speedup vs baseline: 1.4478x; 1.0078x over previous
//
#include <hip/hip_runtime.h>
#include <hip/hip_bf16.h>
#include <stdint.h>

#define VOCAB 10000
#define HID   256
#define BATCH 32
#define STEPS 256

typedef __attribute__((ext_vector_type(8))) short short8;
typedef __attribute__((ext_vector_type(4))) float floatx4;

// keep a loaded value alive in a VGPR: asm becomes the producer, so the
// compiler cannot rematerialize (re-issue) the originating load in-loop.
#define PIN4(v) asm volatile("" : "+v"((v).x), "+v"((v).y), "+v"((v).z), "+v"((v).w))

__device__ __forceinline__ float bf2f(unsigned short u) {
    union { unsigned int ui; float f; } v;
    v.ui = ((unsigned int)u) << 16;
    return v.f;
}

__device__ __forceinline__ unsigned short f2bf(float f) {
    union { float f; unsigned int ui; } v;
    v.f = f;
    unsigned int u = v.ui;
    unsigned int r = (u + 0x7FFFu + ((u >> 16) & 1u)) >> 16;  // RNE
    return (unsigned short)r;
}

// packed bf16x2 dot product: acc += lo(w)*lo(h) + hi(w)*hi(h)
#if __has_builtin(__builtin_amdgcn_fdot2_f32_bf16)
typedef __bf16 bf16x2 __attribute__((ext_vector_type(2)));
__device__ __forceinline__ float dot2(unsigned int w, unsigned int h, float acc) {
    union { unsigned int u; bf16x2 v; } a, b;
    a.u = w; b.u = h;
    return __builtin_amdgcn_fdot2_f32_bf16(a.v, b.v, acc, false);
}
#else
__device__ __forceinline__ float dot2(unsigned int w, unsigned int h, float acc) {
    union { unsigned int u; float f; } w0, w1, h0, h1;
    w0.u = w << 16; w1.u = w & 0xFFFF0000u;
    h0.u = h << 16; h1.u = h & 0xFFFF0000u;
    acc = fmaf(w0.f, h0.f, acc);
    acc = fmaf(w1.f, h1.f, acc);
    return acc;
}
#endif

__device__ __forceinline__ float sigmoidf_(float x) {
    return __builtin_amdgcn_rcpf(1.0f + __expf(-x));
}
__device__ __forceinline__ float tanhf_(float x) {
    // 1 - 2/(exp(2x)+1); correct limits at +-inf with v_exp
    float e = __expf(2.0f * x);
    return 1.0f - 2.0f * __builtin_amdgcn_rcpf(e + 1.0f);
}

// ---------------------------------------------------------------------------
// prep_w: Whz/Whr/Whh f32[256][256] -> Wsw[g][p4(32)][j(256)][m(8)] bf16
// grid (3, 32), 256 thr. Coalesced f32 row reads; contiguous 16B short8 writes.
// ---------------------------------------------------------------------------
__global__ void prep_w(const float* __restrict__ Wz, const float* __restrict__ Wr,
                       const float* __restrict__ Wh, unsigned short* __restrict__ out) {
    int g = blockIdx.x, p4 = blockIdx.y, j = threadIdx.x;
    const float* W = (g == 0) ? Wz : (g == 1) ? Wr : Wh;
    union { unsigned short us[8]; short8 v; } pk;
    #pragma unroll
    for (int m = 0; m < 8; ++m)
        pk.us[m] = f2bf(W[(p4 * 8 + m) * HID + j]);
    *(short8*)(out + (((size_t)g * 32 + p4) * HID + j) * 8) = pk.v;
}

// ---------------------------------------------------------------------------
// prep_b: Whq f32[256][10000] -> B-fragment buffer for mfma_16x16x32_bf16
//   bfr[nt(625)][kc(8)][lane(64)][jj(8)] = Whq[kc*32 + (lane>>4)*8 + jj][nt*16 + (lane&15)]
// grid (40, 8). LDS transpose: coalesced loads -> contiguous 16B short8 writes.
// ---------------------------------------------------------------------------
__global__ void prep_b(const float* __restrict__ Whq, unsigned short* __restrict__ bfr) {
    __shared__ float lds[32][257];   // +1 pad breaks bank aliasing on the gather
    const int nb = blockIdx.x;       // 0..39  (256 cols each)
    const int kc = blockIdx.y;       // 0..7   (32 k-rows each)
    const int tid = threadIdx.x;
    const int n0 = nb * 256;

    #pragma unroll 4
    for (int kk = 0; kk < 32; ++kk) {
        int n = n0 + tid;
        float v = (n < VOCAB) ? Whq[(size_t)(kc * 32 + kk) * VOCAB + n] : 0.0f;
        lds[kk][tid] = v;
    }
    __syncthreads();

    const int lane = tid & 63;
    const int wq   = tid >> 6;       // 0..3
    const int quad = lane >> 4, l15 = lane & 15;
    #pragma unroll
    for (int ntp = 0; ntp < 4; ++ntp) {
        int nt_local = ntp * 4 + wq;
        int nt = nb * 16 + nt_local;
        if (nt >= 625) continue;
        union { unsigned short us[8]; short8 v; } pk;
        #pragma unroll
        for (int jj = 0; jj < 8; ++jj)
            pk.us[jj] = f2bf(lds[quad * 8 + jj][nt_local * 16 + l15]);
        *(short8*)(bfr + (((size_t)nt * 8 + kc) * 64 + lane) * 8) = pk.v;
    }
}

// ---------------------------------------------------------------------------
// prep_a: hist[8192][256] bf16 -> A-fragment buffer Afr[MT(512)][kc(8)][lane(64)][8]
//   Afr[MT][kc][lane][jj] = hist[MT*16 + (lane&15)][kc*32 + (lane>>4)*8 + jj]
// ---------------------------------------------------------------------------
__global__ __launch_bounds__(256) void prep_a(const unsigned short* __restrict__ hist,
                                              unsigned short* __restrict__ afr) {
    __shared__ __align__(16) unsigned short tile[16 * 256];
    const int MT = blockIdx.x;       // 0..511
    const int tid = threadIdx.x;

    const uint4* src = (const uint4*)(hist + (size_t)MT * 16 * 256);
    uint4* dst = (uint4*)tile;
    dst[tid]       = src[tid];
    dst[tid + 256] = src[tid + 256];
    __syncthreads();

    #pragma unroll
    for (int i = 0; i < 2; ++i) {
        int s = tid * 2 + i;         // 0..511 = kc*64 + lane
        int kc = s >> 6, lane = s & 63;
        int quad = lane >> 4, l15 = lane & 15;
        const unsigned short* p = tile + l15 * 256 + kc * 32 + quad * 8;
        *(short8*)(afr + (((size_t)MT * 8 + kc) * 64 + lane) * 8) = *(const short8*)p;
    }
}

// ---------------------------------------------------------------------------
// gru_rec: round-3 split structure + PIN + amdgpu_waves_per_eu(2,2).
// 32 blocks x 512 threads (8 waves = exactly 2 waves/EU).
// waves_per_eu(2,2) pins the allocator's occupancy target at 2 waves/EU ->
// 256-VGPR budget, so the 192 pinned weight regs fit WITHOUT scratch spill
// (R6 evidence: with the default heuristic the allocator kept 120 VGPRs and
// spilled the pinned values to scratch -> per-use reloads, no speedup).
// ---------------------------------------------------------------------------
__global__ __launch_bounds__(512)
__attribute__((amdgpu_waves_per_eu(2, 2)))
void gru_rec(
    const int* __restrict__ X, const float* __restrict__ H0,
    const float* __restrict__ Wxz, const float* __restrict__ Wxr,
    const float* __restrict__ Wxh,
    const float* __restrict__ bz, const float* __restrict__ br,
    const float* __restrict__ bh,
    const unsigned short* __restrict__ Wsw,
    unsigned short* __restrict__ hist,   // [STEPS*BATCH][HID] bf16
    float* __restrict__ h_final)         // [BATCH][HID] f32
{
    const int b = blockIdx.x;
    const int tid = threadIdx.x;
    const bool isA = tid < HID;
    const int j = isA ? tid : tid - HID;

    __shared__ __align__(16) unsigned short hbuf[HID];
    __shared__ __align__(16) unsigned short rhbuf[HID];
    __shared__ float part[HID];
    __shared__ float xrow[2][3][HID];
    __shared__ int Xl[STEPS];

    const uint4* wA = (const uint4*)Wsw + (size_t)(isA ? 0 : 1) * 32 * HID + j; // z or r
    const uint4* wH = (const uint4*)Wsw + (size_t)2 * 32 * HID + j;             // h

    float h_my = H0[b * HID + j];
    float bias = isA ? bz[j] : br[j];
    float bhj  = isA ? bh[j] : 0.0f;

    // ---- hoist loop-invariant weights into registers, then PIN them ----
    uint4 wreg[32];          // full-K column of W_hz (A) / W_hr (B): 128 regs
    #pragma unroll
    for (int i = 0; i < 32; ++i) wreg[i] = wA[i * HID];

    const int i0 = isA ? 0 : 16;
    uint4 whreg[16];         // K-half column of W_hh: 64 regs
    #pragma unroll
    for (int i = 0; i < 16; ++i) whreg[i] = wH[(i0 + i) * HID];

    #pragma unroll
    for (int i = 0; i < 32; ++i) PIN4(wreg[i]);
    #pragma unroll
    for (int i = 0; i < 16; ++i) PIN4(whreg[i]);

    if (isA) { hbuf[j] = f2bf(h_my); Xl[j] = X[b * STEPS + j]; }
    __syncthreads();

    {   // initial x-row gather for t=0
        int x0 = Xl[0];
        if (isA) {
            xrow[0][0][j] = Wxz[(size_t)x0 * HID + j];
            xrow[0][2][j] = Wxh[(size_t)x0 * HID + j];
        } else {
            xrow[0][1][j] = Wxr[(size_t)x0 * HID + j];
        }
    }
    __syncthreads();

    float z = 0.0f;

    for (int t = 0; t < STEPS; ++t) {
        const int cur = t & 1, nxt = cur ^ 1;

        // prefetch next step's x-projection rows (wraps harmlessly at t=255)
        const int xn = Xl[(t + 1) & (STEPS - 1)];
        float p0 = 0.f, p1 = 0.f;
        if (isA) {
            p0 = Wxz[(size_t)xn * HID + j];
            p1 = Wxh[(size_t)xn * HID + j];
        } else {
            p0 = Wxr[(size_t)xn * HID + j];
        }

        // z-gate (A) / r-gate (B): full-K dot over h pairs, weights from VGPRs
        float acc;
        {
            const uint4* hp = (const uint4*)hbuf;
            float a0 = 0.f, a1 = 0.f, a2 = 0.f, a3 = 0.f;
            #pragma unroll
            for (int i = 0; i < 32; ++i) {
                uint4 hv = hp[i];
                a0 = dot2(wreg[i].x, hv.x, a0);
                a1 = dot2(wreg[i].y, hv.y, a1);
                a2 = dot2(wreg[i].z, hv.z, a2);
                a3 = dot2(wreg[i].w, hv.w, a3);
            }
            acc = (a0 + a1) + (a2 + a3);
        }

        if (isA) {
            z = sigmoidf_(acc + xrow[cur][0][j] + bias);
            xrow[nxt][0][j] = p0;
            xrow[nxt][2][j] = p1;
        } else {
            float r = sigmoidf_(acc + xrow[cur][1][j] + bias);
            rhbuf[j] = f2bf(r * h_my);
            xrow[nxt][1][j] = p0;
        }
        __syncthreads();  // B1: rhbuf + xrow[nxt] published

        // h-gate: K split between groups (A: pairs 0..63, B: 64..127)
        float acch;
        {
            const uint4* rp = (const uint4*)rhbuf;
            float a0 = 0.f, a1 = 0.f, a2 = 0.f, a3 = 0.f;
            #pragma unroll
            for (int i = 0; i < 16; ++i) {
                uint4 hv = rp[i0 + i];
                a0 = dot2(whreg[i].x, hv.x, a0);
                a1 = dot2(whreg[i].y, hv.y, a1);
                a2 = dot2(whreg[i].z, hv.z, a2);
                a3 = dot2(whreg[i].w, hv.w, a3);
            }
            acch = (a0 + a1) + (a2 + a3);
        }
        if (!isA) part[j] = acch;
        __syncthreads();  // B2: h-gate partials published

        if (isA) {
            float hpre = acch + part[j] + xrow[cur][2][j] + bhj;
            float ht = tanhf_(hpre);
            float hn = z * h_my + (1.0f - z) * ht;
            h_my = hn;
            unsigned short hb = f2bf(hn);
            hbuf[j] = hb;
            hist[((size_t)t * BATCH + b) * HID + j] = hb;
        }
        __syncthreads();  // B3: hbuf published

        if (!isA) h_my = bf2f(hbuf[j]);  // B's h copy (bf16-rounded, used only for rh)
    }

    if (isA) h_final[b * HID + j] = h_my;
}

// ---------------------------------------------------------------------------
// proj: C[8192][10000] = A[8192][256](bf16) @ B[256][10000](bf16) + bq, f32 out
// UNCHANGED (surfaces to top-5 once gru drops; need its counters).
// ---------------------------------------------------------------------------
__global__ __launch_bounds__(256, 2) void proj(
    const unsigned short* __restrict__ Afr,  // [512][8][64][8]
    const unsigned short* __restrict__ Bfr,  // [625][8][64][8]
    const float* __restrict__ bq,
    float* __restrict__ C)
{
    const int tid  = threadIdx.x;
    const int wave = tid >> 6;
    const int lane = tid & 63;
    const int l15  = lane & 15;
    const int quad = lane >> 4;

    // XCD-aware decode: blocks on one XCD share a 5-nb B-slice, sweep mb.
    const int orig = blockIdx.x;        // 0..2559
    const int xcd  = orig & 7;
    const int idx  = orig >> 3;         // 0..319
    const int mb   = idx / 5;           // 0..63
    const int nb   = xcd * 5 + (idx % 5);  // 0..39

    const int m0 = mb * 128;
    const int nt0 = nb * 16 + wave * 4;

    floatx4 acc[8][4];
    #pragma unroll
    for (int i = 0; i < 8; ++i)
        #pragma unroll
        for (int q = 0; q < 4; ++q)
            acc[i][q] = (floatx4)0.0f;

    int ntc[4];
    #pragma unroll
    for (int q = 0; q < 4; ++q) {
        int nt = nt0 + q;
        ntc[q] = (nt < 625) ? nt : 624;
    }

    for (int kc = 0; kc < 8; ++kc) {
        short8 a[8];
        #pragma unroll
        for (int mt = 0; mt < 8; ++mt) {
            const unsigned short* ap =
                Afr + (((size_t)(mb * 8 + mt) * 8 + kc) * 64 + lane) * 8;
            a[mt] = *(const short8*)ap;
        }
        short8 bfrg[4];
        #pragma unroll
        for (int q = 0; q < 4; ++q) {
            const unsigned short* bp =
                Bfr + ((((size_t)ntc[q] * 8 + kc) * 64) + lane) * 8;
            bfrg[q] = *(const short8*)bp;
        }
        // operands SWAPPED: lane holds C[m0+mt*16+l15][nt*16+quad*4 + r]
        #pragma unroll
        for (int mt = 0; mt < 8; ++mt)
            #pragma unroll
            for (int q = 0; q < 4; ++q)
                acc[mt][q] = __builtin_amdgcn_mfma_f32_16x16x32_bf16(
                    bfrg[q], a[mt], acc[mt][q], 0, 0, 0);
    }

    // epilogue: bias + non-temporal float4 stores (4 consecutive cols per lane)
    floatx4 bq4[4];
    #pragma unroll
    for (int q = 0; q < 4; ++q) {
        int nt = nt0 + q;
        bq4[q] = (nt < 625) ? *(const floatx4*)(bq + nt * 16 + quad * 4)
                            : (floatx4)0.0f;
    }
    #pragma unroll
    for (int mt = 0; mt < 8; ++mt) {
        const size_t rowoff = (size_t)(m0 + mt * 16 + l15) * VOCAB;
        #pragma unroll
        for (int q = 0; q < 4; ++q) {
            int nt = nt0 + q;
            if (nt >= 625) continue;
            floatx4 v = acc[mt][q] + bq4[q];
            __builtin_nontemporal_store(v, (floatx4*)(C + rowoff + nt * 16 + quad * 4));
        }
    }
}

// ---------------------------------------------------------------------------
extern "C" void kernel_launch(void* const* d_in, const int* in_sizes, int n_in,
                              void* d_out, int out_size, void* d_ws, size_t ws_size,
                              hipStream_t stream) {
    const int*   X   = (const int*)  d_in[0];
    const float* H0  = (const float*)d_in[1];
    const float* Wxz = (const float*)d_in[2];
    const float* Whz = (const float*)d_in[3];
    const float* bz  = (const float*)d_in[4];
    const float* Wxr = (const float*)d_in[5];
    const float* Whr = (const float*)d_in[6];
    const float* br  = (const float*)d_in[7];
    const float* Wxh = (const float*)d_in[8];
    const float* Whh = (const float*)d_in[9];
    const float* bh  = (const float*)d_in[10];
    const float* Whq = (const float*)d_in[11];
    const float* bq  = (const float*)d_in[12];

    float* out     = (float*)d_out;
    float* h_final = out + (size_t)STEPS * BATCH * VOCAB;

    // ws layout (ushorts): Wsw[196608] | Bfr[2560000] | hist[2097152] | Afr[2097152]
    unsigned short* wsw  = (unsigned short*)d_ws;
    unsigned short* bfr  = wsw + 196608;
    unsigned short* hist = bfr + 2560000;
    unsigned short* afr  = hist + 2097152;

    prep_w<<<dim3(3, 32), 256, 0, stream>>>(Whz, Whr, Whh, wsw);
    prep_b<<<dim3(40, 8), 256, 0, stream>>>(Whq, bfr);
    gru_rec<<<BATCH, 512, 0, stream>>>(X, H0, Wxz, Wxr, Wxh, bz, br, bh,
                                       wsw, hist, h_final);
    prep_a<<<512, 256, 0, stream>>>(hist, afr);
    proj<<<2560, 256, 0, stream>>>(afr, bfr, bq, out);
}